// Round 6
// baseline (272.496 us; speedup 1.0000x reference)
//
#include <hip/hip_runtime.h>
#include <hip/hip_bf16.h>
#include <math.h>

#define BATCH 128
#define NPRI  8732
#define CCH   512
#define HH    19
#define NHID  4096
#define FGC   19

typedef unsigned short u16;
typedef __attribute__((ext_vector_type(8))) short bf16x8;
typedef __attribute__((ext_vector_type(4))) float f32x4;

// RNE fp32 -> bf16 (finite values)
__device__ __forceinline__ u16 f2bf(float f) {
  unsigned u = __float_as_uint(f);
  u += 0x7fff + ((u >> 16) & 1);
  return (u16)(u >> 16);
}

// ---------------------------------------------------------------------------
// K1a: per-(batch, quarter) partial argmax of car score  (R2 version)
// ---------------------------------------------------------------------------
__global__ void k_best_partial(const float* __restrict__ conf,
                               float* __restrict__ cs, int* __restrict__ ci,
                               int* __restrict__ cc) {
  int blk = blockIdx.x;
  int b = blk >> 2, chunk = blk & 3;
  int n0 = chunk * 2183;
  int t = threadIdx.x;
  const float* cb = conf + (size_t)b * NPRI * 2;
  float bestS = -INFINITY; int bestN = 0x7fffffff; int car_any = 0;
  for (int i = n0 + t; i < n0 + 2183; i += 256) {
    float c0 = cb[2 * i], c1 = cb[2 * i + 1];
    float m = fmaxf(c0, c1);
    float e0 = expf(c0 - m), e1 = expf(c1 - m);
    float s = e0 + e1;
    float p0 = e0 / s, p1 = e1 / s;
    bool car = p1 > p0;
    car_any |= (int)car;
    float sc = car ? p1 : -INFINITY;
    if (sc > bestS || (sc == bestS && i < bestN)) { bestS = sc; bestN = i; }
  }
  __shared__ float ls[256]; __shared__ int li[256]; __shared__ int lc[256];
  ls[t] = bestS; li[t] = bestN; lc[t] = car_any;
  __syncthreads();
  for (int off = 128; off > 0; off >>= 1) {
    if (t < off) {
      float s2 = ls[t + off]; int n2 = li[t + off];
      if (s2 > ls[t] || (s2 == ls[t] && n2 < li[t])) { ls[t] = s2; li[t] = n2; }
      lc[t] |= lc[t + off];
    }
    __syncthreads();
  }
  if (t == 0) { cs[blk] = ls[0]; ci[blk] = li[0]; cc[blk] = lc[0]; }
}

// ---------------------------------------------------------------------------
// K1b: combine + decode + outputs + crop coords (R2) + b3-init of fg_cls
// (k_gemm3f atomically accumulates onto the b3-seeded rows)
// ---------------------------------------------------------------------------
__global__ void k_best_final(const float* __restrict__ loc,
                             const float* __restrict__ priors,
                             const float* __restrict__ cs,
                             const int* __restrict__ ci,
                             const int* __restrict__ cc,
                             const float* __restrict__ b3,
                             float* __restrict__ out,
                             int4* __restrict__ crop,
                             int* __restrict__ vflag) {
  int b = threadIdx.x;
  if (b >= BATCH) return;
  float bs = -INFINITY; int bn = 0; int hc = 0;
  #pragma unroll
  for (int p = 0; p < 4; p++) {
    float s = cs[b * 4 + p]; int n = ci[b * 4 + p];
    hc |= cc[b * 4 + p];
    if (s > bs) { bs = s; bn = n; }
  }
  // seed fg_cls row with bias
  #pragma unroll
  for (int j = 0; j < FGC; j++) out[b * FGC + j] = b3[j];
  const float* lp = loc + ((size_t)b * NPRI + bn) * 4;
  const float* pp = priors + (size_t)bn * 4;
  float l0 = lp[0], l1 = lp[1], l2 = lp[2], l3 = lp[3];
  float pcx = pp[0], pcy = pp[1], pw = pp[2], ph = pp[3];
  float cx = pcx + (l0 * 0.1f) * pw;
  float cy = pcy + (l1 * 0.1f) * ph;
  float w = pw * expf(l2 * 0.2f);
  float h = ph * expf(l3 * 0.2f);
  float x1 = cx - 0.5f * w;
  float y1 = cy - 0.5f * h;
  float x2 = x1 + w, y2 = y1 + h;
  bool geom = (x2 > x1) && (y2 > y1);
  bool valid = hc && geom;
  float r0, r1, r2, r3;
  if (hc) { r0 = x1; r1 = y1; r2 = x2; r3 = y2; }
  else    { r0 = r1 = r2 = r3 = 0.0f; }
  r0 = fminf(fmaxf(r0, 0.0f), 1.0f);
  r1 = fminf(fmaxf(r1, 0.0f), 1.0f);
  r2 = fminf(fmaxf(r2, 0.0f), 1.0f);
  r3 = fminf(fmaxf(r3, 0.0f), 1.0f);
  float* ob = out + BATCH * FGC;
  ob[b * 4 + 0] = r0; ob[b * 4 + 1] = r1;
  ob[b * 4 + 2] = r2; ob[b * 4 + 3] = r3;
  out[BATCH * FGC + BATCH * 4 + b] = valid ? 1.0f : 0.0f;
  const float stepF = (float)(300.0 / 19.0);
  float q0 = fminf(fmaxf(r0 * 300.0f, 0.0f), 300.0f) / stepF;
  float q1 = fminf(fmaxf(r1 * 300.0f, 0.0f), 300.0f) / stepF;
  float q2 = fminf(fmaxf(r2 * 300.0f, 0.0f), 300.0f) / stepF;
  float q3 = fminf(fmaxf(r3 * 300.0f, 0.0f), 300.0f) / stepF;
  int ix1 = (int)floorf(fminf(fmaxf(q0, 0.0f), 18.0f));
  int iy1 = (int)floorf(fminf(fmaxf(q1, 0.0f), 18.0f));
  int ix2 = (int)floorf(fminf(fmaxf(q2, 0.0f), 18.0f));
  int iy2 = (int)floorf(fminf(fmaxf(q3, 0.0f), 18.0f));
  crop[b] = make_int4(ix1, iy1, ix2, iy2);
  vflag[b] = valid ? 1 : 0;
}

// ---------------------------------------------------------------------------
// K2: crop + global max pool -> bf16 feat  (R2 version, unchanged)
// ---------------------------------------------------------------------------
__global__ void k_extract(const float* __restrict__ fin,
                          const int4* __restrict__ crop,
                          const int* __restrict__ vflag,
                          u16* __restrict__ feat) {
  int blk = blockIdx.x;
  int b = blk >> 7;
  int tile = blk & 127;
  int wave = threadIdx.x >> 6;
  int lane = threadIdx.x & 63;
  int c = tile * 4 + wave;
  if (!vflag[b]) {
    if (lane == 0) feat[b * CCH + c] = 0;
    return;
  }
  int4 cr = crop[b];
  int wcnt = cr.z - cr.x + 1;
  int cnt = wcnt * (cr.w - cr.y + 1);
  const float* p = fin + (size_t)(b * CCH + c) * (HH * HH);
  float m = -INFINITY;
  for (int i = lane; i < cnt; i += 64) {
    int yy = cr.y + i / wcnt;
    int xx = cr.x + i % wcnt;
    m = fmaxf(m, p[yy * HH + xx]);
  }
  #pragma unroll
  for (int off = 32; off > 0; off >>= 1) m = fmaxf(m, __shfl_xor(m, off));
  if (lane == 0) feat[b * CCH + c] = f2bf(m);
}

// ---------------------------------------------------------------------------
// K3: GEMM1 single-pass. feat bf16 [128,512] @ w1 fp32 [512,4096] + b1,
// relu, -> h1b bf16. Block = 128m x 16n, full K=512 (nIter=16, dbuf).
// Grid 256 blocks. 4 waves, each 32m x 16n (2 MFMA/iter). No part buffer.
// ---------------------------------------------------------------------------
__global__ __launch_bounds__(256) void k_gemm1f(const u16* __restrict__ A,
                                                const float* __restrict__ W,
                                                const float* __restrict__ b1,
                                                u16* __restrict__ h1b) {
  const int K = 512, N = NHID, BK = 32, ST = 40;
  __shared__ u16 As[2][128 * ST];      // 2 x 10 KB
  __shared__ u16 Bs[2][16 * ST];       // 2 x 1.25 KB
  int t = threadIdx.x, lane = t & 63, wave = t >> 6;
  int q = lane >> 4, r = lane & 15;
  int n0 = blockIdx.x * 16;
  int wm = wave * 32;

  int am = t >> 1, ah = (t & 1) * 16;  // A staging: row, 16-elem half
  int kp = t >> 2, nn = (t & 3) * 4;   // W staging (t<64): k-pair, 4 contig n

  const u16* aptr = A + (size_t)am * K + ah;
  const float* wptr = W + (size_t)(2 * kp) * N + n0 + nn;

  f32x4 acc[2];
  acc[0].x = acc[0].y = acc[0].z = acc[0].w = 0.f;
  acc[1].x = acc[1].y = acc[1].z = acc[1].w = 0.f;

  // prologue
  uint4 a0 = *(const uint4*)aptr;
  uint4 a1 = *(const uint4*)(aptr + 8);
  float4 w0, w1;
  if (t < 64) { w0 = *(const float4*)wptr; w1 = *(const float4*)(wptr + N); }
  *(uint4*)&As[0][am * ST + ah]     = a0;
  *(uint4*)&As[0][am * ST + ah + 8] = a1;
  if (t < 64) {
    unsigned pk0 = (unsigned)f2bf(w0.x) | ((unsigned)f2bf(w1.x) << 16);
    unsigned pk1 = (unsigned)f2bf(w0.y) | ((unsigned)f2bf(w1.y) << 16);
    unsigned pk2 = (unsigned)f2bf(w0.z) | ((unsigned)f2bf(w1.z) << 16);
    unsigned pk3 = (unsigned)f2bf(w0.w) | ((unsigned)f2bf(w1.w) << 16);
    *(unsigned*)&Bs[0][(nn + 0) * ST + 2 * kp] = pk0;
    *(unsigned*)&Bs[0][(nn + 1) * ST + 2 * kp] = pk1;
    *(unsigned*)&Bs[0][(nn + 2) * ST + 2 * kp] = pk2;
    *(unsigned*)&Bs[0][(nn + 3) * ST + 2 * kp] = pk3;
  }

  const int nIter = K / BK;            // 16
  for (int it = 0; it < nIter; it++) {
    int cur = it & 1;
    bool more = (it + 1 < nIter);
    if (more) {
      aptr += BK;
      wptr += (size_t)BK * N;
      a0 = *(const uint4*)aptr;
      a1 = *(const uint4*)(aptr + 8);
      if (t < 64) { w0 = *(const float4*)wptr; w1 = *(const float4*)(wptr + N); }
    }
    __syncthreads();
    bf16x8 af[2], bfr;
    af[0] = *(const bf16x8*)&As[cur][(wm + r) * ST + q * 8];
    af[1] = *(const bf16x8*)&As[cur][(wm + 16 + r) * ST + q * 8];
    bfr   = *(const bf16x8*)&Bs[cur][r * ST + q * 8];
    acc[0] = __builtin_amdgcn_mfma_f32_16x16x32_bf16(af[0], bfr, acc[0], 0, 0, 0);
    acc[1] = __builtin_amdgcn_mfma_f32_16x16x32_bf16(af[1], bfr, acc[1], 0, 0, 0);
    if (more) {
      int nxt = cur ^ 1;
      *(uint4*)&As[nxt][am * ST + ah]     = a0;
      *(uint4*)&As[nxt][am * ST + ah + 8] = a1;
      if (t < 64) {
        unsigned pk0 = (unsigned)f2bf(w0.x) | ((unsigned)f2bf(w1.x) << 16);
        unsigned pk1 = (unsigned)f2bf(w0.y) | ((unsigned)f2bf(w1.y) << 16);
        unsigned pk2 = (unsigned)f2bf(w0.z) | ((unsigned)f2bf(w1.z) << 16);
        unsigned pk3 = (unsigned)f2bf(w0.w) | ((unsigned)f2bf(w1.w) << 16);
        *(unsigned*)&Bs[nxt][(nn + 0) * ST + 2 * kp] = pk0;
        *(unsigned*)&Bs[nxt][(nn + 1) * ST + 2 * kp] = pk1;
        *(unsigned*)&Bs[nxt][(nn + 2) * ST + 2 * kp] = pk2;
        *(unsigned*)&Bs[nxt][(nn + 3) * ST + 2 * kp] = pk3;
      }
    }
  }

  // epilogue: bias + relu + bf16, C row = wm+16i+q*4+reg, col = n0+r
  float bv = b1[n0 + r];
  #pragma unroll
  for (int i = 0; i < 2; i++)
    #pragma unroll
    for (int reg = 0; reg < 4; reg++) {
      int row = wm + 16 * i + q * 4 + reg;
      float v = fmaxf(acc[i][reg] + bv, 0.0f);
      h1b[(size_t)row * N + n0 + r] = f2bf(v);
    }
}

// ---------------------------------------------------------------------------
// K4: GEMM2 bf16 MFMA, dbuf, KSPL=8 (R5 structure). h1b [128,4096] @ w2 ->
// part (8 slices of 128x4096 fp32).
// ---------------------------------------------------------------------------
template <int KSPL>
__global__ __launch_bounds__(256) void k_mfma(const u16* __restrict__ A,
                                              const float* __restrict__ W,
                                              float* __restrict__ part, int K) {
  const int N = 4096;
  const int BK = 32;
  const int ST = 40;
  __shared__ u16 As[2][128 * ST];
  __shared__ u16 Bs[2][64 * ST];
  int nb = blockIdx.x;
  int ks = blockIdx.y;
  int Kper = K / KSPL;
  int k0b = ks * Kper;
  int t = threadIdx.x;
  int lane = t & 63, wave = t >> 6;
  int q = lane >> 4, r = lane & 15;

  int wm = (wave & 1) * 64;
  int wn = (wave >> 1) * 32;
  int n0 = nb * 64;

  int am = t >> 1, ah = (t & 1) * 16;
  int kp = t >> 4;
  int n4 = (t & 15) * 4;

  const u16* aptr = A + (size_t)am * K + k0b + ah;
  const float* wptr = W + (size_t)(k0b + 2 * kp) * N + n0 + n4;

  f32x4 acc[4][2];
  #pragma unroll
  for (int i = 0; i < 4; i++)
    #pragma unroll
    for (int j = 0; j < 2; j++) {
      acc[i][j].x = 0.f; acc[i][j].y = 0.f; acc[i][j].z = 0.f; acc[i][j].w = 0.f;
    }

  uint4 a0 = *(const uint4*)aptr;
  uint4 a1 = *(const uint4*)(aptr + 8);
  float4 w0 = *(const float4*)wptr;
  float4 w1 = *(const float4*)(wptr + N);
  *(uint4*)&As[0][am * ST + ah]     = a0;
  *(uint4*)&As[0][am * ST + ah + 8] = a1;
  {
    unsigned pk0 = (unsigned)f2bf(w0.x) | ((unsigned)f2bf(w1.x) << 16);
    unsigned pk1 = (unsigned)f2bf(w0.y) | ((unsigned)f2bf(w1.y) << 16);
    unsigned pk2 = (unsigned)f2bf(w0.z) | ((unsigned)f2bf(w1.z) << 16);
    unsigned pk3 = (unsigned)f2bf(w0.w) | ((unsigned)f2bf(w1.w) << 16);
    *(unsigned*)&Bs[0][(n4 + 0) * ST + 2 * kp] = pk0;
    *(unsigned*)&Bs[0][(n4 + 1) * ST + 2 * kp] = pk1;
    *(unsigned*)&Bs[0][(n4 + 2) * ST + 2 * kp] = pk2;
    *(unsigned*)&Bs[0][(n4 + 3) * ST + 2 * kp] = pk3;
  }

  const int nIter = Kper / BK;
  for (int it = 0; it < nIter; it++) {
    int cur = it & 1;
    bool more = (it + 1 < nIter);
    if (more) {
      aptr += BK;
      wptr += (size_t)BK * N;
      a0 = *(const uint4*)aptr;
      a1 = *(const uint4*)(aptr + 8);
      w0 = *(const float4*)wptr;
      w1 = *(const float4*)(wptr + N);
    }
    __syncthreads();
    bf16x8 af[4], bfr[2];
    #pragma unroll
    for (int i = 0; i < 4; i++)
      af[i] = *(const bf16x8*)&As[cur][(wm + 16 * i + r) * ST + q * 8];
    #pragma unroll
    for (int j = 0; j < 2; j++)
      bfr[j] = *(const bf16x8*)&Bs[cur][(wn + 16 * j + r) * ST + q * 8];
    #pragma unroll
    for (int i = 0; i < 4; i++)
      #pragma unroll
      for (int j = 0; j < 2; j++)
        acc[i][j] = __builtin_amdgcn_mfma_f32_16x16x32_bf16(af[i], bfr[j],
                                                            acc[i][j], 0, 0, 0);
    if (more) {
      int nxt = cur ^ 1;
      *(uint4*)&As[nxt][am * ST + ah]     = a0;
      *(uint4*)&As[nxt][am * ST + ah + 8] = a1;
      unsigned pk0 = (unsigned)f2bf(w0.x) | ((unsigned)f2bf(w1.x) << 16);
      unsigned pk1 = (unsigned)f2bf(w0.y) | ((unsigned)f2bf(w1.y) << 16);
      unsigned pk2 = (unsigned)f2bf(w0.z) | ((unsigned)f2bf(w1.z) << 16);
      unsigned pk3 = (unsigned)f2bf(w0.w) | ((unsigned)f2bf(w1.w) << 16);
      *(unsigned*)&Bs[nxt][(n4 + 0) * ST + 2 * kp] = pk0;
      *(unsigned*)&Bs[nxt][(n4 + 1) * ST + 2 * kp] = pk1;
      *(unsigned*)&Bs[nxt][(n4 + 2) * ST + 2 * kp] = pk2;
      *(unsigned*)&Bs[nxt][(n4 + 3) * ST + 2 * kp] = pk3;
    }
  }

  float* dst = part + (size_t)ks * (BATCH * N);
  #pragma unroll
  for (int i = 0; i < 4; i++)
    #pragma unroll
    for (int j = 0; j < 2; j++) {
      int col = n0 + wn + 16 * j + r;
      #pragma unroll
      for (int reg = 0; reg < 4; reg++) {
        int row = wm + 16 * i + q * 4 + reg;
        dst[(size_t)row * N + col] = acc[i][j][reg];
      }
    }
}

// ---------------------------------------------------------------------------
// K5: fused finalize + GEMM3. Grid (32 kc, 4 mg). Block: stage w3 chunk
// [128k x 19] in LDS; thread (mrow=t>>3, sub=t&7) sums 8 part slices over its
// 16-k span, +b2, relu, dots with w3; tree-reduce over sub; atomicAdd to out.
// ---------------------------------------------------------------------------
__global__ __launch_bounds__(256) void k_gemm3f(const float* __restrict__ part,
                                                const float* __restrict__ b2,
                                                const float* __restrict__ w3,
                                                float* __restrict__ out) {
  const int KC = 128;                   // k per block
  int kc = blockIdx.x, mg = blockIdx.y;
  int t = threadIdx.x;
  __shared__ float wl[KC * FGC];        // 9728 B
  __shared__ float red[256][FGC];       // 19456 B
  for (int i = t; i < KC * FGC; i += 256) wl[i] = w3[kc * KC * FGC + i];
  __syncthreads();
  int mrow = t >> 3, sub = t & 7;
  int m = mg * 32 + mrow;
  int kk0 = sub * 16;
  int kg = kc * KC + kk0;               // global k (= n of h2)
  // sum 8 part slices over 16 k
  float4 s[4];
  #pragma unroll
  for (int v = 0; v < 4; v++)
    s[v] = *(const float4*)(part + (size_t)m * NHID + kg + 4 * v);
  #pragma unroll
  for (int p = 1; p < 8; p++) {
    const float* pp = part + (size_t)p * (BATCH * NHID) + (size_t)m * NHID + kg;
    #pragma unroll
    for (int v = 0; v < 4; v++) {
      float4 x = *(const float4*)(pp + 4 * v);
      s[v].x += x.x; s[v].y += x.y; s[v].z += x.z; s[v].w += x.w;
    }
  }
  float acc[FGC];
  #pragma unroll
  for (int j = 0; j < FGC; j++) acc[j] = 0.0f;
  #pragma unroll
  for (int v = 0; v < 4; v++) {
    float4 bv = *(const float4*)(b2 + kg + 4 * v);
    float h[4];
    h[0] = fmaxf(s[v].x + bv.x, 0.0f);
    h[1] = fmaxf(s[v].y + bv.y, 0.0f);
    h[2] = fmaxf(s[v].z + bv.z, 0.0f);
    h[3] = fmaxf(s[v].w + bv.w, 0.0f);
    #pragma unroll
    for (int e = 0; e < 4; e++) {
      const float* wp = &wl[(kk0 + 4 * v + e) * FGC];
      #pragma unroll
      for (int j = 0; j < FGC; j++) acc[j] += h[e] * wp[j];
    }
  }
  #pragma unroll
  for (int j = 0; j < FGC; j++) red[t][j] = acc[j];
  __syncthreads();
  for (int off = 4; off > 0; off >>= 1) {
    if (sub < off) {
      #pragma unroll
      for (int j = 0; j < FGC; j++) red[t][j] += red[t + off][j];
    }
    __syncthreads();
  }
  if (sub == 0) {
    #pragma unroll
    for (int j = 0; j < FGC; j++) atomicAdd(&out[m * FGC + j], red[t][j]);
  }
}

// ---------------------------------------------------------------------------
extern "C" void kernel_launch(void* const* d_in, const int* in_sizes, int n_in,
                              void* d_out, int out_size, void* d_ws, size_t ws_size,
                              hipStream_t stream) {
  const float* loc      = (const float*)d_in[0];
  const float* conf     = (const float*)d_in[1];
  const float* priors   = (const float*)d_in[2];
  const float* features = (const float*)d_in[3];
  const float* w1 = (const float*)d_in[4];
  const float* b1 = (const float*)d_in[5];
  const float* w2 = (const float*)d_in[6];
  const float* b2 = (const float*)d_in[7];
  const float* w3 = (const float*)d_in[8];
  const float* b3 = (const float*)d_in[9];
  float* out = (float*)d_out;           // [128*19 fg][128*4 boxes][128 valid]

  char* ws = (char*)d_ws;
  float* part  = (float*)ws;                                    // 16 MB (8 slices)
  u16*   featb = (u16*)(ws + (size_t)16 * 1024 * 1024);         // 128 KB
  u16*   h1b   = (u16*)(ws + (size_t)17 * 1024 * 1024);         // 1 MB
  float* cs    = (float*)(ws + (size_t)18 * 1024 * 1024);
  int*   ci    = (int*)(cs + 512);
  int*   cc    = ci + 512;
  int4*  crop  = (int4*)(cc + 512);
  int*   vfl   = (int*)(crop + BATCH);

  k_best_partial<<<512, 256, 0, stream>>>(conf, cs, ci, cc);
  k_best_final<<<1, 128, 0, stream>>>(loc, priors, cs, ci, cc, b3,
                                      out, crop, vfl);
  k_extract<<<BATCH * (CCH / 4), 256, 0, stream>>>(features, crop, vfl, featb);
  k_gemm1f<<<256, 256, 0, stream>>>(featb, w1, b1, h1b);
  k_mfma<8><<<dim3(64, 8), 256, 0, stream>>>(h1b, w2, part, 4096);
  k_gemm3f<<<dim3(32, 4), 256, 0, stream>>>(part, b2, w3, out);
}